// Round 1
// baseline (317.555 us; speedup 1.0000x reference)
//
#include <hip/hip_runtime.h>
#include <hip/hip_bf16.h>
#include <cstdint>

#define VDIM 10000
#define VPAD 10016          // 313 * 32, zero-padded K for MFMA
#define NROW 4096
#define DDIM 128
#define KSTEPS 313          // ceil(10000/32)
#define KSPLIT 8
#define KCHUNK 40           // ceil(313/8)

typedef __attribute__((ext_vector_type(8))) short bf16x8;
typedef __attribute__((ext_vector_type(4))) float f32x4;

__device__ __forceinline__ unsigned short f2bf(float f) {
    union { float f; unsigned u; } v; v.f = f;
    unsigned u = v.u;
    unsigned r = (u + 0x7FFFu + ((u >> 16) & 1u)) >> 16;  // RNE
    return (unsigned short)r;
}

// ---------------------------------------------------------------------------
// Kernel 1: convert embeddings fp32 [128][10000] -> bf16 [2][128][10016], pad=0
// ---------------------------------------------------------------------------
__global__ __launch_bounds__(256) void convert_emb(
    const float* __restrict__ ec, const float* __restrict__ er,
    unsigned short* __restrict__ out)
{
    int idx8 = (blockIdx.x * 256 + threadIdx.x) * 8;
    const int total = 2 * DDIM * VPAD;
    if (idx8 >= total) return;
    int e   = idx8 / (DDIM * VPAD);
    int rem = idx8 - e * (DDIM * VPAD);
    int row = rem / VPAD;
    int k   = rem - row * VPAD;          // multiple of 8; VDIM%8==0 so no straddle
    unsigned short o[8];
    if (k < VDIM) {
        const float* src = (e ? er : ec) + row * VDIM + k;
        #pragma unroll
        for (int j = 0; j < 8; ++j) o[j] = f2bf(src[j]);
    } else {
        #pragma unroll
        for (int j = 0; j < 8; ++j) o[j] = 0;
    }
    *reinterpret_cast<bf16x8*>(out + idx8) = *reinterpret_cast<const bf16x8*>(o);
}

// ---------------------------------------------------------------------------
// Kernel 2: three GEMMs [4096,10000]x[10000,128] -> reps[3][4096][128] (f32)
// grid = (row-blocks of 64, stream 0..2, k-chunk 0..7); block = 256 (4 waves)
// wave w owns rows [rb*64 + w*16, +16), all 128 cols, one stream, one K-chunk
// ---------------------------------------------------------------------------
__global__ __launch_bounds__(256, 4) void gemm_rep(
    const float* __restrict__ a0, const float* __restrict__ a1,
    const float* __restrict__ a2,
    const unsigned short* __restrict__ emb,   // [2][128][VPAD] bf16
    float* __restrict__ reps)                 // [3][4096][128] f32 (zeroed)
{
    const int rb = blockIdx.x;
    const int s  = blockIdx.y;
    const int kc = blockIdx.z;
    const float* A = (s == 0) ? a0 : (s == 1 ? a1 : a2);
    const unsigned short* E = emb + (size_t)(s == 0 ? 0 : 1) * (DDIM * VPAD);

    const int wave = threadIdx.x >> 6;
    const int lane = threadIdx.x & 63;
    const int l15  = lane & 15;
    const int quad = lane >> 4;

    const int arow = rb * 64 + wave * 16 + l15;       // A row this lane loads
    const float* ap = A + (size_t)arow * VDIM;

    const int kt0 = kc * KCHUNK;
    const int kt1 = (kt0 + KCHUNK < KSTEPS) ? (kt0 + KCHUNK) : KSTEPS;

    f32x4 acc[8];
    #pragma unroll
    for (int ct = 0; ct < 8; ++ct) acc[ct] = (f32x4){0.f, 0.f, 0.f, 0.f};

    #pragma unroll 2
    for (int kt = kt0; kt < kt1; ++kt) {
        const int k0   = kt * 32;
        const int koct = k0 + quad * 8;               // this lane's k-octet
        bf16x8 af = (bf16x8){0, 0, 0, 0, 0, 0, 0, 0};
        if (koct < VDIM) {                            // tail K-step guard
            const f32x4 f0 = *reinterpret_cast<const f32x4*>(ap + koct);
            const f32x4 f1 = *reinterpret_cast<const f32x4*>(ap + koct + 4);
            af[0] = (short)f2bf(f0[0]); af[1] = (short)f2bf(f0[1]);
            af[2] = (short)f2bf(f0[2]); af[3] = (short)f2bf(f0[3]);
            af[4] = (short)f2bf(f1[0]); af[5] = (short)f2bf(f1[1]);
            af[6] = (short)f2bf(f1[2]); af[7] = (short)f2bf(f1[3]);
        }
        #pragma unroll
        for (int ct = 0; ct < 8; ++ct) {
            const bf16x8 bf = *reinterpret_cast<const bf16x8*>(
                E + (size_t)(ct * 16 + l15) * VPAD + koct);
            acc[ct] = __builtin_amdgcn_mfma_f32_16x16x32_bf16(af, bf, acc[ct], 0, 0, 0);
        }
    }

    // epilogue: C/D layout col = lane&15, row = quad*4 + reg
    float* rp = reps + (size_t)s * NROW * DDIM
                     + (size_t)(rb * 64 + wave * 16) * DDIM;
    #pragma unroll
    for (int ct = 0; ct < 8; ++ct) {
        #pragma unroll
        for (int r = 0; r < 4; ++r) {
            atomicAdd(rp + (quad * 4 + r) * DDIM + ct * 16 + l15, acc[ct][r]);
        }
    }
}

// ---------------------------------------------------------------------------
// Kernel 3: f_pos/f_neg row dots + hinge loss. wave-per-row, block = 4 waves
// ---------------------------------------------------------------------------
__global__ __launch_bounds__(256) void finalize(
    const float* __restrict__ reps, float* __restrict__ out)
{
    __shared__ float ls[4];
    const int wid  = threadIdx.x >> 6;
    const int lane = threadIdx.x & 63;
    const int row  = blockIdx.x * 4 + wid;

    const float* c = reps + (size_t)row * DDIM + 2 * lane;
    const float* r = c + (size_t)NROW * DDIM;
    const float* n = r + (size_t)NROW * DDIM;
    const float2 cv = *reinterpret_cast<const float2*>(c);
    const float2 rv = *reinterpret_cast<const float2*>(r);
    const float2 nv = *reinterpret_cast<const float2*>(n);

    float fp = cv.x * rv.x + cv.y * rv.y;
    float fn = cv.x * nv.x + cv.y * nv.y;
    #pragma unroll
    for (int off = 32; off > 0; off >>= 1) {
        fp += __shfl_down(fp, off);
        fn += __shfl_down(fn, off);
    }
    if (lane == 0) {
        out[row]        = fp;
        out[NROW + row] = fn;
        float t = fn - fp + 0.5f;
        ls[wid] = t > 0.f ? t : 0.f;
    }
    __syncthreads();
    if (threadIdx.x == 0)
        atomicAdd(out + 2 * NROW, ls[0] + ls[1] + ls[2] + ls[3]);
}

// ---------------------------------------------------------------------------
extern "C" void kernel_launch(void* const* d_in, const int* in_sizes, int n_in,
                              void* d_out, int out_size, void* d_ws, size_t ws_size,
                              hipStream_t stream)
{
    const float* cb  = (const float*)d_in[0];
    const float* rbb = (const float*)d_in[1];
    const float* nb  = (const float*)d_in[2];
    const float* ce  = (const float*)d_in[3];
    const float* re  = (const float*)d_in[4];
    float* out = (float*)d_out;

    unsigned short* emb = (unsigned short*)d_ws;
    const size_t embBytes = (size_t)2 * DDIM * VPAD * sizeof(unsigned short); // 5,128,192
    float* reps = (float*)((char*)d_ws + embBytes);
    const size_t repBytes = (size_t)3 * NROW * DDIM * sizeof(float);          // 6,291,456

    convert_emb<<<dim3((2 * DDIM * VPAD / 8) / 256), dim3(256), 0, stream>>>(ce, re, emb);
    hipMemsetAsync(reps, 0, repBytes, stream);
    hipMemsetAsync(out + 2 * NROW, 0, sizeof(float), stream);
    gemm_rep<<<dim3(NROW / 64, 3, KSPLIT), dim3(256), 0, stream>>>(cb, rbb, nb, emb, reps);
    finalize<<<dim3(NROW / 4), dim3(256), 0, stream>>>(reps, out);
}

// Round 3
// 178.769 us; speedup vs baseline: 1.7763x; 1.7763x over previous
//
#include <hip/hip_runtime.h>
#include <hip/hip_bf16.h>
#include <cstdint>

#define VDIM 10000
#define VPAD 10016          // 313 * 32, zero-padded K for MFMA
#define NROW 4096
#define DDIM 128
#define KSTEPS 313          // ceil(10000/32)
#define KSPLIT 8
#define KCHUNK 40           // ceil(313/8)

typedef __attribute__((ext_vector_type(8))) short bf16x8;
typedef __attribute__((ext_vector_type(4))) float f32x4;

__device__ __forceinline__ unsigned short f2bf(float f) {
    union { float f; unsigned u; } v; v.f = f;
    unsigned u = v.u;
    unsigned r = (u + 0x7FFFu + ((u >> 16) & 1u)) >> 16;  // RNE
    return (unsigned short)r;
}

// ---------------------------------------------------------------------------
// Kernel 1: convert embeddings fp32 [128][10000] -> bf16 [2][128][10016], pad=0
// ---------------------------------------------------------------------------
__global__ __launch_bounds__(256) void convert_emb(
    const float* __restrict__ ec, const float* __restrict__ er,
    unsigned short* __restrict__ out)
{
    int idx8 = (blockIdx.x * 256 + threadIdx.x) * 8;
    const int total = 2 * DDIM * VPAD;
    if (idx8 >= total) return;
    int e   = idx8 / (DDIM * VPAD);
    int rem = idx8 - e * (DDIM * VPAD);
    int row = rem / VPAD;
    int k   = rem - row * VPAD;          // multiple of 8; VDIM%8==0 so no straddle
    unsigned short o[8];
    if (k < VDIM) {
        const float* src = (e ? er : ec) + row * VDIM + k;
        #pragma unroll
        for (int j = 0; j < 8; ++j) o[j] = f2bf(src[j]);
    } else {
        #pragma unroll
        for (int j = 0; j < 8; ++j) o[j] = 0;
    }
    *reinterpret_cast<bf16x8*>(out + idx8) = *reinterpret_cast<const bf16x8*>(o);
}

// ---------------------------------------------------------------------------
// Kernel 2: three GEMMs [4096,10000]x[10000,128] -> reps[3][4096][128] (f32)
// grid = (32 row-blocks of 128, stream 0..2, k-chunk 0..7); block = 256.
// wave w owns rows [rb*128 + w*32, +32), all 128 cols.
// B K-tile (32k x 128col) is LDS-staged once per block per kt, double-buffered
// (reg-staged: gload next kt while computing current), ONE barrier per kt.
// LDS rows padded to 40 shorts (80B) -> conflict-free ds_read_b128.
// ---------------------------------------------------------------------------
__global__ __launch_bounds__(256, 3) void gemm_rep(
    const float* __restrict__ a0, const float* __restrict__ a1,
    const float* __restrict__ a2,
    const unsigned short* __restrict__ emb,   // [2][128][VPAD] bf16
    float* __restrict__ reps)                 // [3][4096][128] f32 (zeroed)
{
    __shared__ short bLds[2][DDIM][40];       // 20,480 B

    const int rb = blockIdx.x;
    const int s  = blockIdx.y;
    const int kc = blockIdx.z;
    const float* A = (s == 0) ? a0 : (s == 1 ? a1 : a2);
    const unsigned short* E = emb + (size_t)(s == 0 ? 0 : 1) * (DDIM * VPAD);

    const int tid  = threadIdx.x;
    const int wave = tid >> 6;
    const int lane = tid & 63;
    const int l15  = lane & 15;
    const int quad = lane >> 4;

    // staging assignment: thread t owns col=t>>1, half=t&1 (16 shorts = 32B)
    const int scol  = tid >> 1;
    const int shalf = tid & 1;
    const unsigned short* sp = E + (size_t)scol * VPAD + shalf * 16;

    const int kt0 = kc * KCHUNK;
    const int kt1 = (kt0 + KCHUNK < KSTEPS) ? (kt0 + KCHUNK) : KSTEPS;

    const int r0 = rb * 128 + wave * 32;
    const float* ap0 = A + (size_t)(r0 + l15) * VDIM;        // rowfrag 0
    const float* ap1 = A + (size_t)(r0 + 16 + l15) * VDIM;   // rowfrag 1

    f32x4 acc[2][8];
    #pragma unroll
    for (int rf = 0; rf < 2; ++rf)
        #pragma unroll
        for (int ct = 0; ct < 8; ++ct) acc[rf][ct] = (f32x4){0.f, 0.f, 0.f, 0.f};

    bf16x8 s0a, s0b, s1a, s1b;   // two named stage sets (no runtime indexing)

#define GLOADB(sa, sb, KT) do {                                        \
        const unsigned short* q_ = sp + (size_t)(KT) * 32;             \
        sa = *reinterpret_cast<const bf16x8*>(q_);                     \
        sb = *reinterpret_cast<const bf16x8*>(q_ + 8);                 \
    } while (0)

#define DSWRITE(BUF, sa, sb) do {                                      \
        *reinterpret_cast<bf16x8*>(&bLds[BUF][scol][shalf * 16])     = sa; \
        *reinterpret_cast<bf16x8*>(&bLds[BUF][scol][shalf * 16 + 8]) = sb; \
    } while (0)

#define COMPUTE(KT, BUF) do {                                          \
        const int koct_ = (KT) * 32 + quad * 8;                        \
        bf16x8 af0 = (bf16x8){0,0,0,0,0,0,0,0};                        \
        bf16x8 af1 = (bf16x8){0,0,0,0,0,0,0,0};                        \
        if (koct_ < VDIM) {                                            \
            const f32x4 f0 = *reinterpret_cast<const f32x4*>(ap0 + koct_);     \
            const f32x4 f1 = *reinterpret_cast<const f32x4*>(ap0 + koct_ + 4); \
            const f32x4 g0 = *reinterpret_cast<const f32x4*>(ap1 + koct_);     \
            const f32x4 g1 = *reinterpret_cast<const f32x4*>(ap1 + koct_ + 4); \
            af0[0]=(short)f2bf(f0[0]); af0[1]=(short)f2bf(f0[1]);      \
            af0[2]=(short)f2bf(f0[2]); af0[3]=(short)f2bf(f0[3]);      \
            af0[4]=(short)f2bf(f1[0]); af0[5]=(short)f2bf(f1[1]);      \
            af0[6]=(short)f2bf(f1[2]); af0[7]=(short)f2bf(f1[3]);      \
            af1[0]=(short)f2bf(g0[0]); af1[1]=(short)f2bf(g0[1]);      \
            af1[2]=(short)f2bf(g0[2]); af1[3]=(short)f2bf(g0[3]);      \
            af1[4]=(short)f2bf(g1[0]); af1[5]=(short)f2bf(g1[1]);      \
            af1[6]=(short)f2bf(g1[2]); af1[7]=(short)f2bf(g1[3]);      \
        }                                                              \
        bf16x8 bfr[8];                                                 \
        _Pragma("unroll")                                              \
        for (int ct = 0; ct < 8; ++ct)                                 \
            bfr[ct] = *reinterpret_cast<const bf16x8*>(                \
                &bLds[BUF][ct * 16 + l15][quad * 8]);                  \
        _Pragma("unroll")                                              \
        for (int ct = 0; ct < 8; ++ct) {                               \
            acc[0][ct] = __builtin_amdgcn_mfma_f32_16x16x32_bf16(af0, bfr[ct], acc[0][ct], 0, 0, 0); \
            acc[1][ct] = __builtin_amdgcn_mfma_f32_16x16x32_bf16(af1, bfr[ct], acc[1][ct], 0, 0, 0); \
        }                                                              \
    } while (0)

    // prologue: stage kt0 into set 0
    GLOADB(s0a, s0b, kt0);
    int kt = kt0;
    while (true) {
        // even parity: consume set0 -> buf0
        if (kt + 1 < kt1) GLOADB(s1a, s1b, kt + 1);
        DSWRITE(0, s0a, s0b);
        __syncthreads();
        COMPUTE(kt, 0);
        if (++kt >= kt1) break;
        // odd parity: consume set1 -> buf1
        if (kt + 1 < kt1) GLOADB(s0a, s0b, kt + 1);
        DSWRITE(1, s1a, s1b);
        __syncthreads();
        COMPUTE(kt, 1);
        if (++kt >= kt1) break;
    }
    // NOTE on safety: buf written at iter i was last *read* at iter i-2;
    // the barrier at iter i-1 (which waits lgkmcnt) ordered those reads.

    // epilogue: C/D layout col = lane&15, row = quad*4 + reg
    float* rp = reps + (size_t)s * NROW * DDIM + (size_t)r0 * DDIM;
    #pragma unroll
    for (int rf = 0; rf < 2; ++rf)
        #pragma unroll
        for (int ct = 0; ct < 8; ++ct)
            #pragma unroll
            for (int r = 0; r < 4; ++r)
                atomicAdd(rp + (size_t)(rf * 16 + quad * 4 + r) * DDIM + ct * 16 + l15,
                          acc[rf][ct][r]);
#undef GLOADB
#undef DSWRITE
#undef COMPUTE
}

// ---------------------------------------------------------------------------
// Kernel 3: f_pos/f_neg row dots + hinge loss. wave-per-row, block = 4 waves
// ---------------------------------------------------------------------------
__global__ __launch_bounds__(256) void finalize(
    const float* __restrict__ reps, float* __restrict__ out)
{
    __shared__ float ls[4];
    const int wid  = threadIdx.x >> 6;
    const int lane = threadIdx.x & 63;
    const int row  = blockIdx.x * 4 + wid;

    const float* c = reps + (size_t)row * DDIM + 2 * lane;
    const float* r = c + (size_t)NROW * DDIM;
    const float* n = r + (size_t)NROW * DDIM;
    const float2 cv = *reinterpret_cast<const float2*>(c);
    const float2 rv = *reinterpret_cast<const float2*>(r);
    const float2 nv = *reinterpret_cast<const float2*>(n);

    float fp = cv.x * rv.x + cv.y * rv.y;
    float fn = cv.x * nv.x + cv.y * nv.y;
    #pragma unroll
    for (int off = 32; off > 0; off >>= 1) {
        fp += __shfl_down(fp, off);
        fn += __shfl_down(fn, off);
    }
    if (lane == 0) {
        out[row]        = fp;
        out[NROW + row] = fn;
        float t = fn - fp + 0.5f;
        ls[wid] = t > 0.f ? t : 0.f;
    }
    __syncthreads();
    if (threadIdx.x == 0)
        atomicAdd(out + 2 * NROW, ls[0] + ls[1] + ls[2] + ls[3]);
}

// ---------------------------------------------------------------------------
extern "C" void kernel_launch(void* const* d_in, const int* in_sizes, int n_in,
                              void* d_out, int out_size, void* d_ws, size_t ws_size,
                              hipStream_t stream)
{
    const float* cb  = (const float*)d_in[0];
    const float* rbb = (const float*)d_in[1];
    const float* nb  = (const float*)d_in[2];
    const float* ce  = (const float*)d_in[3];
    const float* re  = (const float*)d_in[4];
    float* out = (float*)d_out;

    unsigned short* emb = (unsigned short*)d_ws;
    const size_t embBytes = (size_t)2 * DDIM * VPAD * sizeof(unsigned short); // 5,128,192
    float* reps = (float*)((char*)d_ws + embBytes);
    const size_t repBytes = (size_t)3 * NROW * DDIM * sizeof(float);          // 6,291,456

    convert_emb<<<dim3((2 * DDIM * VPAD / 8) / 256), dim3(256), 0, stream>>>(ce, re, emb);
    hipMemsetAsync(reps, 0, repBytes, stream);
    hipMemsetAsync(out + 2 * NROW, 0, sizeof(float), stream);
    gemm_rep<<<dim3(NROW / 128, 3, KSPLIT), dim3(256), 0, stream>>>(cb, rbb, nb, emb, reps);
    finalize<<<dim3(NROW / 4), dim3(256), 0, stream>>>(reps, out);
}